// Round 14
// baseline (71.626 us; speedup 1.0000x reference)
//
#include <hip/hip_runtime.h>
#include <cmath>

#define NF 4096
#define PI2F 6.2831853071795864769f

typedef float2 cf;

__device__ __forceinline__ cf cmulf(cf a, cf b){
  return make_float2(fmaf(a.x, b.x, -(a.y*b.y)), fmaf(a.x, b.y, a.y*b.x));
}
__device__ __forceinline__ cf cadd(cf a, cf b){ return make_float2(a.x+b.x, a.y+b.y); }
__device__ __forceinline__ cf csub(cf a, cf b){ return make_float2(a.x-b.x, a.y-b.y); }

// ---- k_main LDS map (round 14): span stride 576 (SAME 36 KiB, SAME 4 blk/CU
// as the proven config) + intra-span triangular XOR bijection
//   phi(y) = y ^ ((y>>3)&7) ^ (((y>>6)&3)<<3),  y = i & 511
// Verified per-pattern lane->bank-pair counts (64 lanes, 32 pairs):
//   stage1/2 (y=64B+l):    exactly 2/pair (phys8 was 3-way on 7 pairs)
//   stage3  (y=64g+8q+c):  exactly 2/pair
//   stage4  (y=8l+q):      exactly 2/pair
// 2-way aliasing is the wave64 b64 floor (free, m136). Bijective: high bits
// untouched, XOR masks strictly below their source bits. Wave-privacy: span
// s = i>>9 preserved exactly as before.
__device__ __forceinline__ int physN(int i){
  int y = i & 511;
  int f = y ^ ((y >> 3) & 7) ^ (((y >> 6) & 3) << 3);
  return (i >> 9) * 576 + f;
}

// base-8 digit reversal of a 12-bit index (involution): slot w <-> true freq k
__device__ __forceinline__ int rev8(int i){
  return ((i & 7) << 9) | (((i >> 3) & 7) << 6) | (((i >> 6) & 7) << 3) | ((i >> 9) & 7);
}

// radix-8 DFT in registers; INV=0 forward (e^{-i}), INV=1 inverse (e^{+i}), unnormalized.
template<int INV>
__device__ __forceinline__ void dft8(cf* v){
  const float HF = 0.7071067811865476f;
  cf e0,e1,e2,e3,o0,o1,o2,o3;
  {
    cf t0 = cadd(v[0], v[4]);
    cf t1 = csub(v[0], v[4]);
    cf t2 = cadd(v[2], v[6]);
    cf t3 = csub(v[2], v[6]);
    e0 = cadd(t0,t2); e2 = csub(t0,t2);
    if (!INV){ e1 = make_float2(t1.x+t3.y, t1.y-t3.x); e3 = make_float2(t1.x-t3.y, t1.y+t3.x); }
    else     { e1 = make_float2(t1.x-t3.y, t1.y+t3.x); e3 = make_float2(t1.x+t3.y, t1.y-t3.x); }
  }
  {
    cf t0 = cadd(v[1], v[5]);
    cf t1 = csub(v[1], v[5]);
    cf t2 = cadd(v[3], v[7]);
    cf t3 = csub(v[3], v[7]);
    o0 = cadd(t0,t2); o2 = csub(t0,t2);
    if (!INV){ o1 = make_float2(t1.x+t3.y, t1.y-t3.x); o3 = make_float2(t1.x-t3.y, t1.y+t3.x); }
    else     { o1 = make_float2(t1.x-t3.y, t1.y+t3.x); o3 = make_float2(t1.x+t3.y, t1.y-t3.x); }
  }
  cf w1, w2, w3;
  if (!INV){
    w1 = make_float2(HF*(o1.x + o1.y), HF*(o1.y - o1.x));
    w2 = make_float2(o2.y, -o2.x);
    w3 = make_float2(HF*(o3.y - o3.x), -HF*(o3.x + o3.y));
  } else {
    w1 = make_float2(HF*(o1.x - o1.y), HF*(o1.y + o1.x));
    w2 = make_float2(-o2.y, o2.x);
    w3 = make_float2(-HF*(o3.x + o3.y), HF*(o3.x - o3.y));
  }
  v[0] = cadd(e0,o0); v[4] = csub(e0,o0);
  v[1] = cadd(e1,w1); v[5] = csub(e1,w1);
  v[2] = cadd(e2,w2); v[6] = csub(e2,w2);
  v[3] = cadd(e3,w3); v[7] = csub(e3,w3);
}

// v[r] *= e^{i*ang*r}, r=1..7. Chebyshev power build: T_{r+1} = 2c*T_r - T_{r-1}
__device__ __forceinline__ void twiddle8(cf* v, float ang){
  float s, c;
  __sincosf(ang, &s, &c);
  float c2 = 2.0f * c;
  cf T[8];
  T[1] = make_float2(c, s);
  T[2] = make_float2(fmaf(c2, c, -1.0f), c2 * s);
#pragma unroll
  for (int r = 3; r < 8; ++r)
    T[r] = make_float2(fmaf(c2, T[r-1].x, -T[r-2].x), fmaf(c2, T[r-1].y, -T[r-2].y));
#pragma unroll
  for (int r = 1; r < 8; ++r) v[r] = cmulf(v[r], T[r]);
}

__device__ __forceinline__ float fast_tanh(float x){
  float e = __expf(2.0f*x);
  return 1.0f - __fdividef(2.0f, e + 1.0f);
}

// compiler-only fence: pins LDS phase ordering without any runtime cost
#define PHASE_FENCE() asm volatile("" ::: "memory")

// ---------------- k_mk: fused spectral-table + reduction (round-12 proven) --------
__global__ __launch_bounds__(512,4) void k_mk(
    const float* __restrict__ C, const float* __restrict__ Bb,
    const float* __restrict__ Lam, const float* __restrict__ D,
    cf* __restrict__ M){
  __shared__ cf Wsh[32][64];          // 16 KiB
  __shared__ float4 Tt[8][128];       // 16 KiB
  __shared__ float pcs[4][64];        // 1 KiB: tt, r, numr, numi per p
  const int t  = threadIdx.x;
  const int hg = blockIdx.x >> 5;     // 0..7
  const int ls = blockIdx.x & 31;     // 0..31
  const int h0 = hg*32;
  const int w0 = ls*128;
#pragma unroll
  for (int e = 0; e < 4; ++e){
    int idx = e*512 + t;
    int hl = idx >> 6, p = idx & 63;
    int h = h0 + hl;
    cf cc = ((const cf*)C)[h*64 + p];
    cf bb = ((const cf*)Bb)[p*256 + h];
    Wsh[hl][p] = cmulf(cc, bb);
  }
  if (t < 64){
    int p = t;
    double lr = (double)Lam[2*p], li = (double)Lam[2*p+1];
    double r2 = lr*lr + li*li;
    double tt = atan2(li, lr) * 0.15915494309189535;   // phase in turns
    double rN = exp2(4096.0 * (0.5 * log2(r2)));       // |lambda|^N
    double pN = 4096.0 * tt;  pN -= floor(pN);
    double sN, cN;  sincospi(2.0*pN, &sN, &cN);
    pcs[0][p] = (float)tt;
    pcs[1][p] = (float)sqrt(r2);
    pcs[2][p] = (float)(1.0 - rN*cN);                  // num.re
    pcs[3][p] = (float)(-rN*sN);                       // num.im
  }
  const int wave = t >> 6;
  const int lane = t & 63;
  const int hh = wave*4;              // this wave's 4 local h
  const float hN = 0.5f/4096.0f;
  float accr[2][4] = {{0,0,0,0},{0,0,0,0}};
  float acci[2][4] = {{0,0,0,0},{0,0,0,0}};
  for (int pc = 0; pc < 8; ++pc){
    __syncthreads();
#pragma unroll
    for (int e = 0; e < 2; ++e){
      int idx = e*512 + t;
      int row = idx >> 7, col = idx & 127;
      int p = pc*8 + row;
      float tt = pcs[0][p], r = pcs[1][p], numr = pcs[2][p], numi = pcs[3][p];
      int w = w0 + col;
      int k = rev8(w);
      float kf = (float)k * (1.0f/4096.0f);
      float s1, c1;  sincospif(2.0f*(tt - kf), &s1, &c1);
      float d1r = fmaf(-r, c1, 1.0f), d1i = -r*s1;
      float i1 = 1.0f / fmaf(d1r, d1r, d1i*d1i);
      float g1r = (numr*d1r + numi*d1i)*i1;
      float g1i = (numi*d1r - numr*d1i)*i1;
      float s2, c2;  sincospif(2.0f*(tt + kf), &s2, &c2);
      float d2r = fmaf(-r, c2, 1.0f), d2i = -r*s2;
      float i2 = 1.0f / fmaf(d2r, d2r, d2i*d2i);
      float g2r = (numr*d2r + numi*d2i)*i2;
      float g2i = (numi*d2r - numr*d2i)*i2;
      Tt[row][col] = make_float4( (g1r + g2r)*hN, (g1i - g2i)*hN,
                                 -(g1i + g2i)*hN, (g1r - g2r)*hN);
    }
    __syncthreads();
#pragma unroll
    for (int p = 0; p < 8; ++p){
      cf Wc[4];
#pragma unroll
      for (int h = 0; h < 4; ++h) Wc[h] = Wsh[hh + h][pc*8 + p];   // broadcast
#pragma unroll
      for (int j = 0; j < 2; ++j){
        float4 f = Tt[p][lane + 64*j];
#pragma unroll
        for (int h = 0; h < 4; ++h){
          accr[j][h] = fmaf(Wc[h].x, f.x, fmaf(Wc[h].y, f.z, accr[j][h]));
          acci[j][h] = fmaf(Wc[h].x, f.y, fmaf(Wc[h].y, f.w, acci[j][h]));
        }
      }
    }
  }
  const float invN = 1.0f/4096.0f;
#pragma unroll
  for (int h = 0; h < 4; ++h){
    int hq = h0 + hh + h;
    float dd = D[hq*256 + hq] * invN;
#pragma unroll
    for (int j = 0; j < 2; ++j)
      M[(size_t)hq*NF + w0 + lane + 64*j] = make_float2(accr[j][h] + dd, acci[j][h]);
  }
}

// ------------- main: z = u0 + i u1 ; FFT ; *M ; IFFT ; tanh ; store ------------------
// Round-13 2-barrier structure (proven) + round-14 conflict-free LDS map.
// Everything else byte-identical to the proven 52us config.
__global__ __launch_bounds__(512,8) void k_main(
    const float* __restrict__ u, const cf* __restrict__ M, float* __restrict__ out){
  __shared__ cf X[4608];                 // 36 KiB (same size/occupancy as proven)
  const int t  = threadIdx.x;
  const int h  = blockIdx.x >> 3;
  const int pr = blockIdx.x & 7;
  const size_t row0 = ((size_t)pr*256 + h)*(size_t)NF;
  const size_t row1 = row0 + (size_t)8*256*NF;
  const float* u0 = u + row0;
  const float* u1 = u + row1;
  cf v[8];
  // fwd stage 1 (span 4096) — cross-wave scatter
#pragma unroll
  for (int q = 0; q < 8; ++q) v[q] = make_float2(u0[t + 512*q], u1[t + 512*q]);
  dft8<0>(v);
  twiddle8(v, -(PI2F/4096.0f)*(float)t);
#pragma unroll
  for (int r = 0; r < 8; ++r) X[physN(t + 512*r)] = v[r];
  __syncthreads();                       // BARRIER 1 of 2
  // fwd stage 2 (span 512) — wave-private
  const int b2 = ((t >> 6) << 9) | (t & 63);
#pragma unroll
  for (int q = 0; q < 8; ++q) v[q] = X[physN(b2 + 64*q)];
  dft8<0>(v);
  twiddle8(v, -(PI2F/512.0f)*(float)(t & 63));
#pragma unroll
  for (int r = 0; r < 8; ++r) X[physN(b2 + 64*r)] = v[r];
  PHASE_FENCE();
  // fwd stage 3 (span 64) — wave-private
  const int b3 = ((t >> 3) << 6) | (t & 7);
#pragma unroll
  for (int q = 0; q < 8; ++q) v[q] = X[physN(b3 + 8*q)];
  dft8<0>(v);
  twiddle8(v, -(PI2F/64.0f)*(float)(t & 7));
#pragma unroll
  for (int r = 0; r < 8; ++r) X[physN(b3 + 8*r)] = v[r];
  PHASE_FENCE();
  // M loads just before stage 4 (PROVEN placement; hoist spills — round 10)
  float4 mf0, mf1;
  {
    const float4* Mr = (const float4*)(M + (size_t)h*NF + 8*t);
    mf0 = Mr[0]; mf1 = Mr[1];
  }
  // fwd stage 4 (span 8) + pointwise + inv stage 1', in registers — wave-private
#pragma unroll
  for (int q = 0; q < 8; ++q) v[q] = X[physN(8*t + q)];
  dft8<0>(v);
  {
    const float4* Mr = (const float4*)(M + (size_t)h*NF + 8*t);
    float4 f2 = Mr[2], f3 = Mr[3];
    v[0] = cmulf(v[0], make_float2(mf0.x, mf0.y));
    v[1] = cmulf(v[1], make_float2(mf0.z, mf0.w));
    v[2] = cmulf(v[2], make_float2(mf1.x, mf1.y));
    v[3] = cmulf(v[3], make_float2(mf1.z, mf1.w));
    v[4] = cmulf(v[4], make_float2(f2.x, f2.y));
    v[5] = cmulf(v[5], make_float2(f2.z, f2.w));
    v[6] = cmulf(v[6], make_float2(f3.x, f3.y));
    v[7] = cmulf(v[7], make_float2(f3.z, f3.w));
  }
  dft8<1>(v);
#pragma unroll
  for (int q = 0; q < 8; ++q) X[physN(8*t + q)] = v[q];
  PHASE_FENCE();
  // inv stage 3 — wave-private
#pragma unroll
  for (int r = 0; r < 8; ++r) v[r] = X[physN(b3 + 8*r)];
  twiddle8(v, (PI2F/64.0f)*(float)(t & 7));
  dft8<1>(v);
#pragma unroll
  for (int q = 0; q < 8; ++q) X[physN(b3 + 8*q)] = v[q];
  PHASE_FENCE();
  // inv stage 2 — wave-private writes, then cross-wave reads follow
#pragma unroll
  for (int r = 0; r < 8; ++r) v[r] = X[physN(b2 + 64*r)];
  twiddle8(v, (PI2F/512.0f)*(float)(t & 63));
  dft8<1>(v);
#pragma unroll
  for (int q = 0; q < 8; ++q) X[physN(b2 + 64*q)] = v[q];
  __syncthreads();                       // BARRIER 2 of 2
  // inv stage 1 (span 4096) + epilogue — cross-wave gather
#pragma unroll
  for (int r = 0; r < 8; ++r) v[r] = X[physN(t + 512*r)];
  twiddle8(v, (PI2F/4096.0f)*(float)t);
  dft8<1>(v);
  float* o0 = out + row0;
  float* o1 = out + row1;
#pragma unroll
  for (int q = 0; q < 8; ++q){
    o0[t + 512*q] = fast_tanh(v[q].x);
    o1[t + 512*q] = fast_tanh(v[q].y);
  }
}

extern "C" void kernel_launch(void* const* d_in, const int* in_sizes, int n_in,
                              void* d_out, int out_size, void* d_ws, size_t ws_size,
                              hipStream_t stream){
  const float* u   = (const float*)d_in[0];
  const float* C   = (const float*)d_in[1];
  const float* D   = (const float*)d_in[2];
  const float* Bb  = (const float*)d_in[3];
  const float* Lam = (const float*)d_in[4];
  float* out = (float*)d_out;
  char* ws = (char*)d_ws;
  cf* M = (cf*)ws;                    // 8 MiB: [256][4096] cf, rev8 slot order

  k_mk  <<<dim3(256),  dim3(512), 0, stream>>>(C, Bb, Lam, D, M);
  k_main<<<dim3(2048), dim3(512), 0, stream>>>(u, M, out);
}

// Round 15
// 62.959 us; speedup vs baseline: 1.1377x; 1.1377x over previous
//
#include <hip/hip_runtime.h>
#include <cmath>

#define NF 4096
#define PI2F 6.2831853071795864769f

typedef float2 cf;

__device__ __forceinline__ cf cmulf(cf a, cf b){
  return make_float2(fmaf(a.x, b.x, -(a.y*b.y)), fmaf(a.x, b.y, a.y*b.x));
}
__device__ __forceinline__ cf cadd(cf a, cf b){ return make_float2(a.x+b.x, a.y+b.y); }
__device__ __forceinline__ cf csub(cf a, cf b){ return make_float2(a.x-b.x, a.y-b.y); }

// ---- k_main LDS map: additive pad. PROVEN 52us config (rounds 5/6/8/9/11/13).
// Round-14 lesson: the conflict-free XOR map zeroes SQ_LDS_BANK_CONFLICT but its
// address arithmetic spills at the pinned 32-VGPR allocation (+61MB scratch) and
// conflicts were hidden under dependency stalls anyway. Keep the cheap map.
__device__ __forceinline__ int phys8(int i){ return i + (i >> 3); }

// base-8 digit reversal of a 12-bit index (involution): slot w <-> true freq k
__device__ __forceinline__ int rev8(int i){
  return ((i & 7) << 9) | (((i >> 3) & 7) << 6) | (((i >> 6) & 7) << 3) | ((i >> 9) & 7);
}

// radix-8 DFT in registers; INV=0 forward (e^{-i}), INV=1 inverse (e^{+i}), unnormalized.
template<int INV>
__device__ __forceinline__ void dft8(cf* v){
  const float HF = 0.7071067811865476f;
  cf e0,e1,e2,e3,o0,o1,o2,o3;
  {
    cf t0 = cadd(v[0], v[4]);
    cf t1 = csub(v[0], v[4]);
    cf t2 = cadd(v[2], v[6]);
    cf t3 = csub(v[2], v[6]);
    e0 = cadd(t0,t2); e2 = csub(t0,t2);
    if (!INV){ e1 = make_float2(t1.x+t3.y, t1.y-t3.x); e3 = make_float2(t1.x-t3.y, t1.y+t3.x); }
    else     { e1 = make_float2(t1.x-t3.y, t1.y+t3.x); e3 = make_float2(t1.x+t3.y, t1.y-t3.x); }
  }
  {
    cf t0 = cadd(v[1], v[5]);
    cf t1 = csub(v[1], v[5]);
    cf t2 = cadd(v[3], v[7]);
    cf t3 = csub(v[3], v[7]);
    o0 = cadd(t0,t2); o2 = csub(t0,t2);
    if (!INV){ o1 = make_float2(t1.x+t3.y, t1.y-t3.x); o3 = make_float2(t1.x-t3.y, t1.y+t3.x); }
    else     { o1 = make_float2(t1.x-t3.y, t1.y+t3.x); o3 = make_float2(t1.x+t3.y, t1.y-t3.x); }
  }
  cf w1, w2, w3;
  if (!INV){
    w1 = make_float2(HF*(o1.x + o1.y), HF*(o1.y - o1.x));
    w2 = make_float2(o2.y, -o2.x);
    w3 = make_float2(HF*(o3.y - o3.x), -HF*(o3.x + o3.y));
  } else {
    w1 = make_float2(HF*(o1.x - o1.y), HF*(o1.y + o1.x));
    w2 = make_float2(-o2.y, o2.x);
    w3 = make_float2(-HF*(o3.x + o3.y), HF*(o3.x - o3.y));
  }
  v[0] = cadd(e0,o0); v[4] = csub(e0,o0);
  v[1] = cadd(e1,w1); v[5] = csub(e1,w1);
  v[2] = cadd(e2,w2); v[6] = csub(e2,w2);
  v[3] = cadd(e3,w3); v[7] = csub(e3,w3);
}

// v[r] *= e^{i*ang*r}, r=1..7. Chebyshev power build: T_{r+1} = 2c*T_r - T_{r-1}
__device__ __forceinline__ void twiddle8(cf* v, float ang){
  float s, c;
  __sincosf(ang, &s, &c);
  float c2 = 2.0f * c;
  cf T[8];
  T[1] = make_float2(c, s);
  T[2] = make_float2(fmaf(c2, c, -1.0f), c2 * s);
#pragma unroll
  for (int r = 3; r < 8; ++r)
    T[r] = make_float2(fmaf(c2, T[r-1].x, -T[r-2].x), fmaf(c2, T[r-1].y, -T[r-2].y));
#pragma unroll
  for (int r = 1; r < 8; ++r) v[r] = cmulf(v[r], T[r]);
}

__device__ __forceinline__ float fast_tanh(float x){
  float e = __expf(2.0f*x);
  return 1.0f - __fdividef(2.0f, e + 1.0f);
}

// compiler-only fence: pins LDS phase ordering without any runtime cost
#define PHASE_FENCE() asm volatile("" ::: "memory")

// ---------------- k_mk: fused spectral-table + reduction (round-12 proven) --------
__global__ __launch_bounds__(512,4) void k_mk(
    const float* __restrict__ C, const float* __restrict__ Bb,
    const float* __restrict__ Lam, const float* __restrict__ D,
    cf* __restrict__ M){
  __shared__ cf Wsh[32][64];          // 16 KiB
  __shared__ float4 Tt[8][128];       // 16 KiB
  __shared__ float pcs[4][64];        // 1 KiB: tt, r, numr, numi per p
  const int t  = threadIdx.x;
  const int hg = blockIdx.x >> 5;     // 0..7
  const int ls = blockIdx.x & 31;     // 0..31
  const int h0 = hg*32;
  const int w0 = ls*128;
#pragma unroll
  for (int e = 0; e < 4; ++e){
    int idx = e*512 + t;
    int hl = idx >> 6, p = idx & 63;
    int h = h0 + hl;
    cf cc = ((const cf*)C)[h*64 + p];
    cf bb = ((const cf*)Bb)[p*256 + h];
    Wsh[hl][p] = cmulf(cc, bb);
  }
  if (t < 64){
    int p = t;
    double lr = (double)Lam[2*p], li = (double)Lam[2*p+1];
    double r2 = lr*lr + li*li;
    double tt = atan2(li, lr) * 0.15915494309189535;   // phase in turns
    double rN = exp2(4096.0 * (0.5 * log2(r2)));       // |lambda|^N
    double pN = 4096.0 * tt;  pN -= floor(pN);
    double sN, cN;  sincospi(2.0*pN, &sN, &cN);
    pcs[0][p] = (float)tt;
    pcs[1][p] = (float)sqrt(r2);
    pcs[2][p] = (float)(1.0 - rN*cN);                  // num.re
    pcs[3][p] = (float)(-rN*sN);                       // num.im
  }
  const int wave = t >> 6;
  const int lane = t & 63;
  const int hh = wave*4;              // this wave's 4 local h
  const float hN = 0.5f/4096.0f;
  float accr[2][4] = {{0,0,0,0},{0,0,0,0}};
  float acci[2][4] = {{0,0,0,0},{0,0,0,0}};
  for (int pc = 0; pc < 8; ++pc){
    __syncthreads();
#pragma unroll
    for (int e = 0; e < 2; ++e){
      int idx = e*512 + t;
      int row = idx >> 7, col = idx & 127;
      int p = pc*8 + row;
      float tt = pcs[0][p], r = pcs[1][p], numr = pcs[2][p], numi = pcs[3][p];
      int w = w0 + col;
      int k = rev8(w);
      float kf = (float)k * (1.0f/4096.0f);
      float s1, c1;  sincospif(2.0f*(tt - kf), &s1, &c1);
      float d1r = fmaf(-r, c1, 1.0f), d1i = -r*s1;
      float i1 = 1.0f / fmaf(d1r, d1r, d1i*d1i);
      float g1r = (numr*d1r + numi*d1i)*i1;
      float g1i = (numi*d1r - numr*d1i)*i1;
      float s2, c2;  sincospif(2.0f*(tt + kf), &s2, &c2);
      float d2r = fmaf(-r, c2, 1.0f), d2i = -r*s2;
      float i2 = 1.0f / fmaf(d2r, d2r, d2i*d2i);
      float g2r = (numr*d2r + numi*d2i)*i2;
      float g2i = (numi*d2r - numr*d2i)*i2;
      Tt[row][col] = make_float4( (g1r + g2r)*hN, (g1i - g2i)*hN,
                                 -(g1i + g2i)*hN, (g1r - g2r)*hN);
    }
    __syncthreads();
#pragma unroll
    for (int p = 0; p < 8; ++p){
      cf Wc[4];
#pragma unroll
      for (int h = 0; h < 4; ++h) Wc[h] = Wsh[hh + h][pc*8 + p];   // broadcast
#pragma unroll
      for (int j = 0; j < 2; ++j){
        float4 f = Tt[p][lane + 64*j];
#pragma unroll
        for (int h = 0; h < 4; ++h){
          accr[j][h] = fmaf(Wc[h].x, f.x, fmaf(Wc[h].y, f.z, accr[j][h]));
          acci[j][h] = fmaf(Wc[h].x, f.y, fmaf(Wc[h].y, f.w, acci[j][h]));
        }
      }
    }
  }
  const float invN = 1.0f/4096.0f;
#pragma unroll
  for (int h = 0; h < 4; ++h){
    int hq = h0 + hh + h;
    float dd = D[hq*256 + hq] * invN;
#pragma unroll
    for (int j = 0; j < 2; ++j)
      M[(size_t)hq*NF + w0 + lane + 64*j] = make_float2(accr[j][h] + dd, acci[j][h]);
  }
}

// ------------- main: z = u0 + i u1 ; FFT ; *M ; IFFT ; tanh ; store ------------------
// ROUND-13 PROVEN FORM, byte-for-byte (best total 63.0us). 2 barriers + phys8.
__global__ __launch_bounds__(512,8) void k_main(
    const float* __restrict__ u, const cf* __restrict__ M, float* __restrict__ out){
  __shared__ cf X[4608];                 // 36 KiB
  const int t  = threadIdx.x;
  const int h  = blockIdx.x >> 3;
  const int pr = blockIdx.x & 7;
  const size_t row0 = ((size_t)pr*256 + h)*(size_t)NF;
  const size_t row1 = row0 + (size_t)8*256*NF;
  const float* u0 = u + row0;
  const float* u1 = u + row1;
  cf v[8];
  // fwd stage 1 (span 4096) — cross-wave scatter
#pragma unroll
  for (int q = 0; q < 8; ++q) v[q] = make_float2(u0[t + 512*q], u1[t + 512*q]);
  dft8<0>(v);
  twiddle8(v, -(PI2F/4096.0f)*(float)t);
#pragma unroll
  for (int r = 0; r < 8; ++r) X[phys8(t + 512*r)] = v[r];
  __syncthreads();                       // BARRIER 1 of 2
  // fwd stage 2 (span 512) — wave-private
  const int b2 = ((t >> 6) << 9) | (t & 63);
#pragma unroll
  for (int q = 0; q < 8; ++q) v[q] = X[phys8(b2 + 64*q)];
  dft8<0>(v);
  twiddle8(v, -(PI2F/512.0f)*(float)(t & 63));
#pragma unroll
  for (int r = 0; r < 8; ++r) X[phys8(b2 + 64*r)] = v[r];
  PHASE_FENCE();
  // fwd stage 3 (span 64) — wave-private
  const int b3 = ((t >> 3) << 6) | (t & 7);
#pragma unroll
  for (int q = 0; q < 8; ++q) v[q] = X[phys8(b3 + 8*q)];
  dft8<0>(v);
  twiddle8(v, -(PI2F/64.0f)*(float)(t & 7));
#pragma unroll
  for (int r = 0; r < 8; ++r) X[phys8(b3 + 8*r)] = v[r];
  PHASE_FENCE();
  // M loads just before stage 4 (PROVEN placement; hoist spills — round 10)
  float4 mf0, mf1;
  {
    const float4* Mr = (const float4*)(M + (size_t)h*NF + 8*t);
    mf0 = Mr[0]; mf1 = Mr[1];
  }
  // fwd stage 4 (span 8) + pointwise + inv stage 1', in registers — wave-private
#pragma unroll
  for (int q = 0; q < 8; ++q) v[q] = X[phys8(8*t + q)];
  dft8<0>(v);
  {
    const float4* Mr = (const float4*)(M + (size_t)h*NF + 8*t);
    float4 f2 = Mr[2], f3 = Mr[3];
    v[0] = cmulf(v[0], make_float2(mf0.x, mf0.y));
    v[1] = cmulf(v[1], make_float2(mf0.z, mf0.w));
    v[2] = cmulf(v[2], make_float2(mf1.x, mf1.y));
    v[3] = cmulf(v[3], make_float2(mf1.z, mf1.w));
    v[4] = cmulf(v[4], make_float2(f2.x, f2.y));
    v[5] = cmulf(v[5], make_float2(f2.z, f2.w));
    v[6] = cmulf(v[6], make_float2(f3.x, f3.y));
    v[7] = cmulf(v[7], make_float2(f3.z, f3.w));
  }
  dft8<1>(v);
#pragma unroll
  for (int q = 0; q < 8; ++q) X[phys8(8*t + q)] = v[q];
  PHASE_FENCE();
  // inv stage 3 — wave-private
#pragma unroll
  for (int r = 0; r < 8; ++r) v[r] = X[phys8(b3 + 8*r)];
  twiddle8(v, (PI2F/64.0f)*(float)(t & 7));
  dft8<1>(v);
#pragma unroll
  for (int q = 0; q < 8; ++q) X[phys8(b3 + 8*q)] = v[q];
  PHASE_FENCE();
  // inv stage 2 — wave-private writes, then cross-wave reads follow
#pragma unroll
  for (int r = 0; r < 8; ++r) v[r] = X[phys8(b2 + 64*r)];
  twiddle8(v, (PI2F/512.0f)*(float)(t & 63));
  dft8<1>(v);
#pragma unroll
  for (int q = 0; q < 8; ++q) X[phys8(b2 + 64*q)] = v[q];
  __syncthreads();                       // BARRIER 2 of 2
  // inv stage 1 (span 4096) + epilogue — cross-wave gather
#pragma unroll
  for (int r = 0; r < 8; ++r) v[r] = X[phys8(t + 512*r)];
  twiddle8(v, (PI2F/4096.0f)*(float)t);
  dft8<1>(v);
  float* o0 = out + row0;
  float* o1 = out + row1;
#pragma unroll
  for (int q = 0; q < 8; ++q){
    o0[t + 512*q] = fast_tanh(v[q].x);
    o1[t + 512*q] = fast_tanh(v[q].y);
  }
}

extern "C" void kernel_launch(void* const* d_in, const int* in_sizes, int n_in,
                              void* d_out, int out_size, void* d_ws, size_t ws_size,
                              hipStream_t stream){
  const float* u   = (const float*)d_in[0];
  const float* C   = (const float*)d_in[1];
  const float* D   = (const float*)d_in[2];
  const float* Bb  = (const float*)d_in[3];
  const float* Lam = (const float*)d_in[4];
  float* out = (float*)d_out;
  char* ws = (char*)d_ws;
  cf* M = (cf*)ws;                    // 8 MiB: [256][4096] cf, rev8 slot order

  k_mk  <<<dim3(256),  dim3(512), 0, stream>>>(C, Bb, Lam, D, M);
  k_main<<<dim3(2048), dim3(512), 0, stream>>>(u, M, out);
}